// Round 3
// baseline (181.373 us; speedup 1.0000x reference)
//
#include <hip/hip_runtime.h>

#define EPS_ 1e-8f

// sizes: B=16, N=2048, D=128, NS=8, H=128, steps=4
constexpr int OFF_K     = 0;                       // 16*2048*128 = 4194304
constexpr int OFF_WQT   = 4194304;                 // 16384
constexpr int OFF_WKT   = OFF_WQT  + 16384;
constexpr int OFF_WIHT  = OFF_WKT  + 16384;        // 49152
constexpr int OFF_WHHT  = OFF_WIHT + 49152;        // 49152
constexpr int OFF_WM1T  = OFF_WHHT + 49152;        // 16384
constexpr int OFF_WM2T  = OFF_WM1T + 16384;        // 16384
constexpr int OFF_WO1T  = OFF_WM2T + 16384;        // 65536
constexpr int OFF_WO2T  = OFF_WO1T + 65536;        // 32768
constexpr int OFF_SLOTS = OFF_WO2T + 32768;        // 32768
constexpr int OFF_PI    = OFF_SLOTS+ 32768;        // 128
constexpr int OFF_MUS   = OFF_PI   + 128;          // 16384
constexpr int OFF_QMU   = OFF_MUS  + 16384;        // 16384
constexpr int OFF_IVAR  = OFF_QMU  + 16384;        // 16384
constexpr int OFF_UN    = OFF_IVAR + 16384;        // 262144
constexpr int OFF_S2    = OFF_UN   + 262144;       // 262144
constexpr int OFF_DEN   = OFF_S2   + 262144;       // 2048

// ---------------------------------------------------------------------------
__global__ __launch_bounds__(256) void init_kernel(
    const float* __restrict__ Wq,  const float* __restrict__ Wk,
    const float* __restrict__ Wih, const float* __restrict__ Whh,
    const float* __restrict__ Wm1, const float* __restrict__ Wm2,
    const float* __restrict__ Wo1, const float* __restrict__ Wo2,
    const float* __restrict__ smu, const float* __restrict__ sls,
    const float* __restrict__ noise, float* __restrict__ ws) {
  int idx = blockIdx.x * 256 + threadIdx.x;
  if (idx < 16384) { int j = idx >> 7, d = idx & 127; ws[OFF_WQT + d*128 + j] = Wq[idx]; return; }
  idx -= 16384;
  if (idx < 16384) { int j = idx >> 7, d = idx & 127; ws[OFF_WKT + d*128 + j] = Wk[idx]; return; }
  idx -= 16384;
  if (idx < 49152) { int j = idx >> 7, d = idx & 127; ws[OFF_WIHT + d*384 + j] = Wih[idx]; return; }
  idx -= 49152;
  if (idx < 49152) { int j = idx >> 7, d = idx & 127; ws[OFF_WHHT + d*384 + j] = Whh[idx]; return; }
  idx -= 49152;
  if (idx < 16384) { int j = idx >> 7, d = idx & 127; ws[OFF_WM1T + d*128 + j] = Wm1[idx]; return; }
  idx -= 16384;
  if (idx < 16384) { int j = idx >> 7, d = idx & 127; ws[OFF_WM2T + d*128 + j] = Wm2[idx]; return; }
  idx -= 16384;
  if (idx < 65536) { int j = idx >> 8, d = idx & 255; ws[OFF_WO1T + d*256 + j] = Wo1[idx]; return; }
  idx -= 65536;
  if (idx < 32768) { int j = idx >> 8, m = idx & 255; ws[OFF_WO2T + m*128 + j] = Wo2[idx]; return; }
  idx -= 32768;
  if (idx < 32768) { int c = idx & 255; ws[OFF_SLOTS + idx] = smu[c] + expf(sls[c]) * noise[idx]; return; }
  idx -= 32768;
  if (idx < 128) { ws[OFF_PI + idx] = 0.125f; }
}

// ---------------------------------------------------------------------------
// k = LN(inputs) @ Wk.T   (64 rows per block, 512 blocks)
// xs padded to 129 floats/row -> lane=row b32 reads are conflict-free (2/bank)
// WkT staged linear float4 -> wave-uniform broadcast reads in GEMM loop
__global__ __launch_bounds__(256) void k_kernel(
    const float* __restrict__ xin, const float* __restrict__ g, const float* __restrict__ bb,
    const float* __restrict__ WkT, float* __restrict__ kout) {
  __shared__ float xs[64][129];
  __shared__ float4 wt4[128 * 32];
  __shared__ float2 red2[64][4];
  __shared__ float mrow[64], srow[64];
  int t = threadIdx.x;
  long long base = (long long)blockIdx.x * 64 * 128;
  const float4* in4 = (const float4*)(xin + base);
  // stage x (coalesced global, scalar LDS writes)
  for (int f = t; f < 2048; f += 256) {
    float4 v = in4[f];
    int r = f >> 5, gg = (f & 31) * 4;
    xs[r][gg] = v.x; xs[r][gg + 1] = v.y; xs[r][gg + 2] = v.z; xs[r][gg + 3] = v.w;
  }
  // stage WkT (linear, conflict-free)
  const float4* w4 = (const float4*)WkT;
  for (int f = t; f < 4096; f += 256) wt4[f] = w4[f];
  __syncthreads();
  // row stats: thread (r = t>>2, qq = t&3) over 32 elems
  {
    int r = t >> 2, qq = t & 3;
    float s = 0.f, ss = 0.f;
    #pragma unroll 8
    for (int u = 0; u < 32; ++u) { float v = xs[r][qq * 32 + u]; s += v; ss = fmaf(v, v, ss); }
    red2[r][qq] = make_float2(s, ss);
  }
  __syncthreads();
  if (t < 64) {
    float s = 0.f, ss = 0.f;
    #pragma unroll
    for (int qq = 0; qq < 4; ++qq) { float2 p = red2[t][qq]; s += p.x; ss += p.y; }
    float m = s * (1.0f / 128.0f);
    float var = ss * (1.0f / 128.0f) - m * m;
    mrow[t] = m; srow[t] = rsqrtf(var + 1e-5f);
  }
  __syncthreads();
  {
    int r = t >> 2, qq = t & 3;
    float m = mrow[r], is = srow[r];
    #pragma unroll 8
    for (int u = 0; u < 32; ++u) {
      int d = qq * 32 + u;
      xs[r][d] = (xs[r][d] - m) * is * g[d] + bb[d];
    }
  }
  __syncthreads();
  // GEMM: lane=row (conflict-free b32 x), 32 j per thread (uniform w reads)
  int r = t & 63, jg = t >> 6;
  float acc[32];
  #pragma unroll
  for (int i = 0; i < 32; ++i) acc[i] = 0.f;
  #pragma unroll 2
  for (int d = 0; d < 128; ++d) {
    float xv = xs[r][d];
    #pragma unroll
    for (int i = 0; i < 8; ++i) {
      float4 wv = wt4[d * 32 + jg * 8 + i];
      acc[i * 4 + 0] = fmaf(xv, wv.x, acc[i * 4 + 0]);
      acc[i * 4 + 1] = fmaf(xv, wv.y, acc[i * 4 + 1]);
      acc[i * 4 + 2] = fmaf(xv, wv.z, acc[i * 4 + 2]);
      acc[i * 4 + 3] = fmaf(xv, wv.w, acc[i * 4 + 3]);
    }
  }
  float* orow = kout + base + (long long)r * 128 + jg * 32;
  #pragma unroll
  for (int i = 0; i < 8; ++i)
    *(float4*)(orow + i * 4) = make_float4(acc[i*4], acc[i*4+1], acc[i*4+2], acc[i*4+3]);
}

// ---------------------------------------------------------------------------
// S1 standalone (first iteration only)
__global__ __launch_bounds__(256) void s1_kernel(
    const float* __restrict__ slots, const float* __restrict__ g, const float* __restrict__ bb,
    const float* __restrict__ WqT, float* __restrict__ mus, float* __restrict__ qmu,
    float* __restrict__ ivar) {
  __shared__ float sl[256];
  __shared__ float2 wr[4];
  int t = threadIdx.x, bi = blockIdx.x;
  float v = slots[bi * 256 + t];
  float s = v, ss = v * v;
  #pragma unroll
  for (int o = 32; o > 0; o >>= 1) { s += __shfl_down(s, o); ss += __shfl_down(ss, o); }
  if ((t & 63) == 0) wr[t >> 6] = make_float2(s, ss);
  __syncthreads();
  float fs  = wr[0].x + wr[1].x + wr[2].x + wr[3].x;
  float fss = wr[0].y + wr[1].y + wr[2].y + wr[3].y;
  float m   = fs * (1.0f/256.0f);
  float var = fss * (1.0f/256.0f) - m * m;
  float isr = rsqrtf(var + 1e-5f);
  float sn  = (v - m) * isr * g[t] + bb[t];
  sl[t] = sn;
  __syncthreads();
  if (t < 128) {
    float acc = 0.f;
    #pragma unroll 4
    for (int d = 0; d < 128; ++d) acc = fmaf(sl[d], WqT[d * 128 + t], acc);
    qmu[bi * 128 + t] = acc;
    mus[bi * 128 + t] = sn;
  } else {
    int jj = t - 128;
    float acc = 0.f;
    #pragma unroll 4
    for (int d = 0; d < 128; ++d) acc = fmaf(sl[128 + d], WqT[d * 128 + jj], acc);
    ivar[bi * 128 + jj] = expf(-2.0f * acc);
  }
}

// ---------------------------------------------------------------------------
// S2: per (b, 128-row n-chunk): dots -> gammas -> partials.
// kc stored granule-swizzled: (n,g) lives at kc4[n*32 + (g ^ (n&31))].
// Phase1: wave w -> slot-pair (w&3), n-half ((w>>2)&1), d-half (w>>3);
//         q/ivar reads wave-uniform, k reads conflict-free b128.
__global__ __launch_bounds__(1024) void s2_kernel(
    const float* __restrict__ kmat, const float* __restrict__ qmu,
    const float* __restrict__ ivar, const float* __restrict__ pi,
    float* __restrict__ wun, float* __restrict__ ws2, float* __restrict__ wden) {
  __shared__ float4 kc4[128 * 32];          // 64KB swizzled k tile
  __shared__ float4 qs4[8 * 32];            // 4KB
  __shared__ float4 ivs4[8 * 32];           // 4KB
  __shared__ float esp[2][8][128];          // 8KB partial dots
  __shared__ float es_[8][128];             // 4KB
  __shared__ float gam_[128][8];            // 4KB
  __shared__ float recip[128];
  __shared__ float pis[8];
  __shared__ float pU[4][8][128];           // 16KB
  __shared__ float pS[4][8][128];           // 16KB
  __shared__ float pd[8][8];
  int t = threadIdx.x;
  int chunk = blockIdx.x, b = blockIdx.y;
  if (t < 8) pis[t] = pi[b * 8 + t];
  if (t < 256) {
    qs4[t]  = ((const float4*)qmu)[b * 256 + t];
    ivs4[t] = ((const float4*)ivar)[b * 256 + t];
  }
  const float4* k4 = (const float4*)(kmat + (long long)(b * 2048 + chunk * 128) * 128);
  for (int f = t; f < 4096; f += 1024) {
    int n = f >> 5, gg = f & 31;
    kc4[n * 32 + (gg ^ (n & 31))] = k4[f];
  }
  __syncthreads();
  // ---- phase 1: partial dots (each wave: 2 slots x 64 n x 64 d)
  {
    int w = t >> 6, lane = t & 63;
    int sp = w & 3, nh = (w >> 2) & 1, dh = w >> 3;
    int s0 = sp * 2, s1 = s0 + 1;
    int n = nh * 64 + lane;
    int nx = n & 31;
    const float4* kr = kc4 + n * 32;
    float acc0 = 0.f, acc1 = 0.f;
    #pragma unroll
    for (int gi = 0; gi < 16; ++gi) {
      int gg = dh * 16 + gi;
      float4 kv = kr[gg ^ nx];
      float4 q0 = qs4[s0 * 32 + gg], i0 = ivs4[s0 * 32 + gg];
      float4 q1 = qs4[s1 * 32 + gg], i1 = ivs4[s1 * 32 + gg];
      float e;
      e = kv.x - q0.x; acc0 = fmaf(e * e, i0.x, acc0);
      e = kv.y - q0.y; acc0 = fmaf(e * e, i0.y, acc0);
      e = kv.z - q0.z; acc0 = fmaf(e * e, i0.z, acc0);
      e = kv.w - q0.w; acc0 = fmaf(e * e, i0.w, acc0);
      e = kv.x - q1.x; acc1 = fmaf(e * e, i1.x, acc1);
      e = kv.y - q1.y; acc1 = fmaf(e * e, i1.y, acc1);
      e = kv.z - q1.z; acc1 = fmaf(e * e, i1.z, acc1);
      e = kv.w - q1.w; acc1 = fmaf(e * e, i1.w, acc1);
    }
    esp[dh][s0][n] = acc0;
    esp[dh][s1][n] = acc1;
  }
  __syncthreads();
  // combine halves + exp
  {
    int s = t >> 7, n = t & 127;
    float dots = esp[0][s][n] + esp[1][s][n];
    es_[s][n] = (expf(-dots) + EPS_) * pis[s];
  }
  __syncthreads();
  if (t < 128) {
    float ssum = 0.f;
    #pragma unroll
    for (int s = 0; s < 8; ++s) ssum += es_[s][t];
    recip[t] = 1.0f / ssum;
  }
  __syncthreads();
  { int s = t >> 7, n = t & 127;
    gam_[n][s] = es_[s][n] * recip[n]; }
  __syncthreads();
  // ---- phase 2: 4 n-groups of 32; per thread all 8 slots at one d
  if (t < 512) {
    int grp = t >> 7, dd = t & 127;
    const float* kcf = (const float*)kc4;
    float un[8] = {0,0,0,0,0,0,0,0};
    float s2[8] = {0,0,0,0,0,0,0,0};
    int gbase = dd >> 2, elem = dd & 3;
    #pragma unroll 2
    for (int n = grp * 32; n < grp * 32 + 32; ++n) {
      float kk  = kcf[n * 128 + 4 * (gbase ^ (n & 31)) + elem];
      float kk2 = kk * kk;
      float4 g0 = *(const float4*)&gam_[n][0];
      float4 g1 = *(const float4*)&gam_[n][4];
      un[0] = fmaf(g0.x, kk, un[0]); s2[0] = fmaf(g0.x, kk2, s2[0]);
      un[1] = fmaf(g0.y, kk, un[1]); s2[1] = fmaf(g0.y, kk2, s2[1]);
      un[2] = fmaf(g0.z, kk, un[2]); s2[2] = fmaf(g0.z, kk2, s2[2]);
      un[3] = fmaf(g0.w, kk, un[3]); s2[3] = fmaf(g0.w, kk2, s2[3]);
      un[4] = fmaf(g1.x, kk, un[4]); s2[4] = fmaf(g1.x, kk2, s2[4]);
      un[5] = fmaf(g1.y, kk, un[5]); s2[5] = fmaf(g1.y, kk2, s2[5]);
      un[6] = fmaf(g1.z, kk, un[6]); s2[6] = fmaf(g1.z, kk2, s2[6]);
      un[7] = fmaf(g1.w, kk, un[7]); s2[7] = fmaf(g1.w, kk2, s2[7]);
    }
    #pragma unroll
    for (int i = 0; i < 8; ++i) { pU[grp][i][dd] = un[i]; pS[grp][i][dd] = s2[i]; }
  } else if (t < 576) {
    int i = (t - 512) & 7, sub = (t - 512) >> 3;
    float dsum = 0.f;
    for (int n = sub * 16; n < sub * 16 + 16; ++n) dsum += gam_[n][i];
    pd[sub][i] = dsum;
  }
  __syncthreads();
  { int i = t >> 7, dd = t & 127;
    int pbase = ((b * 16 + chunk) * 8 + i) * 128 + dd;
    wun[pbase] = pU[0][i][dd] + pU[1][i][dd] + pU[2][i][dd] + pU[3][i][dd];
    ws2[pbase] = pS[0][i][dd] + pS[1][i][dd] + pS[2][i][dd] + pS[3][i][dd]; }
  if (t < 8) {
    float s = 0.f;
    #pragma unroll
    for (int sub = 0; sub < 8; ++sub) s += pd[sub][t];
    wden[(b * 16 + chunk) * 8 + t] = s;
  }
}

// ---------------------------------------------------------------------------
// S3 fused: reduce + GRU + LN + MLP + upd_ls + slots/pi; then next-iter S1
// or the final output MLP. 512 threads, one block per (b,slot).
__global__ __launch_bounds__(512) void s3_kernel(
    const float* __restrict__ wun, const float* __restrict__ ws2, const float* __restrict__ wden,
    const float* __restrict__ WihT, const float* __restrict__ WhhT,
    const float* __restrict__ bih,  const float* __restrict__ bhh,
    const float* __restrict__ Wm1T, const float* __restrict__ bm1,
    const float* __restrict__ Wm2T, const float* __restrict__ bm2,
    const float* __restrict__ gmu,  const float* __restrict__ bmu,
    float* __restrict__ slots, float* __restrict__ pi,
    int do_s1,
    const float* __restrict__ gs, const float* __restrict__ bs,
    const float* __restrict__ WqT,
    float* __restrict__ mus, float* __restrict__ qmu, float* __restrict__ ivar,
    const float* __restrict__ Wo1T, const float* __restrict__ bo1,
    const float* __restrict__ Wo2T, const float* __restrict__ bo2,
    float* __restrict__ out) {
  int t = threadIdx.x, bi = blockIdx.x;
  int d = t & 127, q = t >> 7;      // q in [0,4)
  int b = bi >> 3, i = bi & 7;
  __shared__ float redU[4][128], redS[4][128];
  __shared__ float dred[16];
  __shared__ float xs[128], hs[128];
  __shared__ float gacc[4][6][128];
  __shared__ float ga[6][128];
  __shared__ float grus[128], hl[128], m1s[128];
  __shared__ float macc[4][128];
  __shared__ float2 wr2[2];
  __shared__ float uarr[256];
  float unp = 0.f, s2p = 0.f;
  #pragma unroll
  for (int c = q * 4; c < q * 4 + 4; ++c) {
    int po = ((b * 16 + c) * 8 + i) * 128 + d;
    unp += wun[po]; s2p += ws2[po];
  }
  redU[q][d] = unp; redS[q][d] = s2p;
  if (t < 16) dred[t] = wden[(b * 16 + t) * 8 + i];
  if (q == 1) hs[d] = mus[bi * 128 + d];
  __syncthreads();
  float den = 0.f;
  #pragma unroll
  for (int c = 0; c < 16; ++c) den += dred[c];
  float un  = redU[0][d] + redU[1][d] + redU[2][d] + redU[3][d];
  float s2v = redS[0][d] + redS[1][d] + redS[2][d] + redS[3][d];
  if (q == 0) xs[d] = un / den;
  __syncthreads();
  {
    float a0 = 0, a1 = 0, a2 = 0, a3 = 0, a4 = 0, a5 = 0;
    #pragma unroll 4
    for (int dd = q * 32; dd < q * 32 + 32; ++dd) {
      float xv = xs[dd], hv = hs[dd];
      const float* wi = &WihT[dd * 384 + d];
      const float* wh = &WhhT[dd * 384 + d];
      a0 = fmaf(xv, wi[0],   a0);
      a1 = fmaf(xv, wi[128], a1);
      a2 = fmaf(xv, wi[256], a2);
      a3 = fmaf(hv, wh[0],   a3);
      a4 = fmaf(hv, wh[128], a4);
      a5 = fmaf(hv, wh[256], a5);
    }
    gacc[q][0][d] = a0; gacc[q][1][d] = a1; gacc[q][2][d] = a2;
    gacc[q][3][d] = a3; gacc[q][4][d] = a4; gacc[q][5][d] = a5;
  }
  __syncthreads();
  for (int f = t; f < 768; f += 512) {
    int j = f >> 7, dd = f & 127;
    ga[j][dd] = gacc[0][j][dd] + gacc[1][j][dd] + gacc[2][j][dd] + gacc[3][j][dd];
  }
  __syncthreads();
  float gru = 0.f;
  if (q == 0) {
    float ir = ga[0][d] + bih[d], iz = ga[1][d] + bih[128 + d], inn = ga[2][d] + bih[256 + d];
    float hr = ga[3][d] + bhh[d], hz = ga[4][d] + bhh[128 + d], hn  = ga[5][d] + bhh[256 + d];
    float r  = 1.0f / (1.0f + expf(-(ir + hr)));
    float z  = 1.0f / (1.0f + expf(-(iz + hz)));
    float nn = tanhf(inn + r * hn);
    gru = (1.0f - z) * nn + z * hs[d];
    grus[d] = gru;
    float s = gru, ssq = gru * gru;
    #pragma unroll
    for (int o = 32; o > 0; o >>= 1) { s += __shfl_down(s, o); ssq += __shfl_down(ssq, o); }
    if ((d & 63) == 0) wr2[d >> 6] = make_float2(s, ssq);
  }
  __syncthreads();
  if (q == 0) {
    float fs = wr2[0].x + wr2[1].x, fss = wr2[0].y + wr2[1].y;
    float mean = fs * (1.0f/128.0f);
    float var  = fss * (1.0f/128.0f) - mean * mean;
    hl[d] = (gru - mean) * rsqrtf(var + 1e-5f) * gmu[d] + bmu[d];
  }
  __syncthreads();
  {
    float m1p = 0.f;
    #pragma unroll 4
    for (int dd = q * 32; dd < q * 32 + 32; ++dd)
      m1p = fmaf(hl[dd], Wm1T[dd * 128 + d], m1p);
    macc[q][d] = m1p;
  }
  __syncthreads();
  if (q == 0) m1s[d] = fmaxf(macc[0][d] + macc[1][d] + macc[2][d] + macc[3][d] + bm1[d], 0.f);
  __syncthreads();
  {
    float m2p = 0.f;
    #pragma unroll 4
    for (int dd = q * 32; dd < q * 32 + 32; ++dd)
      m2p = fmaf(m1s[dd], Wm2T[dd * 128 + d], m2p);
    macc[q][d] = m2p;
  }
  __syncthreads();
  if (q == 0) {
    float u = grus[d] + macc[0][d] + macc[1][d] + macc[2][d] + macc[3][d] + bm2[d];
    float val = (s2v - 2.0f * u * un + u * u * den) / den;
    float ls = 0.5f * logf(fmaxf(val, 0.0f) + EPS_);
    slots[bi * 256 + d]       = u;
    slots[bi * 256 + 128 + d] = ls;
    uarr[d] = u; uarr[128 + d] = ls;
    if (d == 0) pi[bi] = den;
  }
  __syncthreads();
  if (do_s1) {
    __shared__ float2 wr4[4];
    __shared__ float sln[256];
    __shared__ float qacc[2][2][128];
    if (t < 256) {
      float v = uarr[t];
      float s = v, ssq = v * v;
      #pragma unroll
      for (int o = 32; o > 0; o >>= 1) { s += __shfl_down(s, o); ssq += __shfl_down(ssq, o); }
      if ((t & 63) == 0) wr4[t >> 6] = make_float2(s, ssq);
    }
    __syncthreads();
    if (t < 256) {
      float fs  = wr4[0].x + wr4[1].x + wr4[2].x + wr4[3].x;
      float fss = wr4[0].y + wr4[1].y + wr4[2].y + wr4[3].y;
      float m   = fs * (1.0f/256.0f);
      float var = fss * (1.0f/256.0f) - m * m;
      sln[t] = (uarr[t] - m) * rsqrtf(var + 1e-5f) * gs[t] + bs[t];
    }
    __syncthreads();
    {
      int h2 = t >> 8, qq = (t >> 7) & 1, d2 = t & 127;
      const float* src = sln + h2 * 128;
      float acc = 0.f;
      #pragma unroll 4
      for (int dd = qq * 64; dd < qq * 64 + 64; ++dd)
        acc = fmaf(src[dd], WqT[dd * 128 + d2], acc);
      qacc[h2][qq][d2] = acc;
    }
    __syncthreads();
    if (t < 128) {
      qmu[bi * 128 + t] = qacc[0][0][t] + qacc[0][1][t];
      mus[bi * 128 + t] = sln[t];
    } else if (t < 256) {
      int dd2 = t - 128;
      ivar[bi * 128 + dd2] = expf(-2.0f * (qacc[1][0][dd2] + qacc[1][1][dd2]));
    }
  } else {
    __shared__ float oacc[2][256];
    __shared__ float hh[256];
    {
      int o = t & 255, qq = t >> 8;
      float acc = 0.f;
      #pragma unroll 4
      for (int dd = qq * 128; dd < qq * 128 + 128; ++dd)
        acc = fmaf(uarr[dd], Wo1T[dd * 256 + o], acc);
      oacc[qq][o] = acc;
    }
    __syncthreads();
    if (t < 256) hh[t] = fmaxf(oacc[0][t] + oacc[1][t] + bo1[t], 0.f);
    __syncthreads();
    {
      int o2 = t & 127, q4 = t >> 7;
      float acc2 = 0.f;
      #pragma unroll 4
      for (int dd = q4 * 64; dd < q4 * 64 + 64; ++dd)
        acc2 = fmaf(hh[dd], Wo2T[dd * 128 + o2], acc2);
      macc[q4][o2] = acc2;
    }
    __syncthreads();
    if (t < 128) out[bi * 128 + t] = macc[0][t] + macc[1][t] + macc[2][t] + macc[3][t] + bo2[t];
  }
}

// ---------------------------------------------------------------------------
extern "C" void kernel_launch(void* const* d_in, const int* in_sizes, int n_in,
                              void* d_out, int out_size, void* d_ws, size_t ws_size,
                              hipStream_t stream) {
  const float* inputs = (const float*)d_in[0];
  const float* noise  = (const float*)d_in[1];
  const float* smu    = (const float*)d_in[2];
  const float* sls    = (const float*)d_in[3];
  const float* Wq     = (const float*)d_in[4];
  const float* Wk     = (const float*)d_in[5];
  const float* Wih    = (const float*)d_in[6];
  const float* Whh    = (const float*)d_in[7];
  const float* bih    = (const float*)d_in[8];
  const float* bhh    = (const float*)d_in[9];
  const float* Wm1    = (const float*)d_in[10];
  const float* bm1    = (const float*)d_in[11];
  const float* Wm2    = (const float*)d_in[12];
  const float* bm2    = (const float*)d_in[13];
  const float* gin    = (const float*)d_in[14];
  const float* bin    = (const float*)d_in[15];
  const float* gsl    = (const float*)d_in[16];
  const float* bsl    = (const float*)d_in[17];
  const float* gmu    = (const float*)d_in[18];
  const float* bmu    = (const float*)d_in[19];
  const float* Wo1    = (const float*)d_in[20];
  const float* bo1    = (const float*)d_in[21];
  const float* Wo2    = (const float*)d_in[22];
  const float* bo2    = (const float*)d_in[23];

  float* ws    = (float*)d_ws;
  float* kbuf  = ws + OFF_K;
  float* WqT   = ws + OFF_WQT;
  float* WkT   = ws + OFF_WKT;
  float* WihT  = ws + OFF_WIHT;
  float* WhhT  = ws + OFF_WHHT;
  float* Wm1T  = ws + OFF_WM1T;
  float* Wm2T  = ws + OFF_WM2T;
  float* Wo1T  = ws + OFF_WO1T;
  float* Wo2T  = ws + OFF_WO2T;
  float* slots = ws + OFF_SLOTS;
  float* pibuf = ws + OFF_PI;
  float* mus   = ws + OFF_MUS;
  float* qmu   = ws + OFF_QMU;
  float* ivar  = ws + OFF_IVAR;
  float* wun   = ws + OFF_UN;
  float* ws2   = ws + OFF_S2;
  float* wden  = ws + OFF_DEN;

  hipLaunchKernelGGL(init_kernel, dim3(1153), dim3(256), 0, stream,
                     Wq, Wk, Wih, Whh, Wm1, Wm2, Wo1, Wo2, smu, sls, noise, ws);
  hipLaunchKernelGGL(k_kernel, dim3(512), dim3(256), 0, stream,
                     inputs, gin, bin, WkT, kbuf);
  hipLaunchKernelGGL(s1_kernel, dim3(128), dim3(256), 0, stream,
                     slots, gsl, bsl, WqT, mus, qmu, ivar);
  for (int s = 0; s < 4; ++s) {
    hipLaunchKernelGGL(s2_kernel, dim3(16, 16), dim3(1024), 0, stream,
                       kbuf, qmu, ivar, pibuf, wun, ws2, wden);
    hipLaunchKernelGGL(s3_kernel, dim3(128), dim3(512), 0, stream,
                       wun, ws2, wden, WihT, WhhT, bih, bhh,
                       Wm1T, bm1, Wm2T, bm2, gmu, bmu, slots, pibuf,
                       (s < 3) ? 1 : 0, gsl, bsl, WqT, mus, qmu, ivar,
                       Wo1T, bo1, Wo2T, bo2, (float*)d_out);
  }
}

// Round 4
// 174.031 us; speedup vs baseline: 1.0422x; 1.0422x over previous
//
#include <hip/hip_runtime.h>

#define EPS_ 1e-8f

// sizes: B=16, N=2048, D=128, NS=8, H=128, steps=4
constexpr int OFF_K     = 0;                       // 16*2048*128 = 4194304
constexpr int OFF_WQT   = 4194304;                 // 16384
constexpr int OFF_WKT   = OFF_WQT  + 16384;
constexpr int OFF_WIHT  = OFF_WKT  + 16384;        // 49152
constexpr int OFF_WHHT  = OFF_WIHT + 49152;        // 49152
constexpr int OFF_WM1T  = OFF_WHHT + 49152;        // 16384
constexpr int OFF_WM2T  = OFF_WM1T + 16384;        // 16384
constexpr int OFF_WO1T  = OFF_WM2T + 16384;        // 65536
constexpr int OFF_WO2T  = OFF_WO1T + 65536;        // 32768
constexpr int OFF_SLOTS = OFF_WO2T + 32768;        // 32768
constexpr int OFF_PI    = OFF_SLOTS+ 32768;        // 128
constexpr int OFF_MUS   = OFF_PI   + 128;          // 16384
constexpr int OFF_WA    = OFF_MUS  + 16384;        // 16384 (iv)
constexpr int OFF_WB    = OFF_WA   + 16384;        // 16384 (-2*q*iv)
constexpr int OFF_UN    = OFF_WB   + 16384;        // 16*32*8*128 = 524288
constexpr int OFF_S2    = OFF_UN   + 524288;       // 524288
constexpr int OFF_DEN   = OFF_S2   + 524288;       // 16*32*8 = 4096
constexpr int OFF_CZ    = OFF_DEN  + 4096;         // 128

// ---------------------------------------------------------------------------
__global__ __launch_bounds__(256) void init_kernel(
    const float* __restrict__ Wq,  const float* __restrict__ Wk,
    const float* __restrict__ Wih, const float* __restrict__ Whh,
    const float* __restrict__ Wm1, const float* __restrict__ Wm2,
    const float* __restrict__ Wo1, const float* __restrict__ Wo2,
    const float* __restrict__ smu, const float* __restrict__ sls,
    const float* __restrict__ noise, float* __restrict__ ws) {
  int idx = blockIdx.x * 256 + threadIdx.x;
  if (idx < 16384) { int j = idx >> 7, d = idx & 127; ws[OFF_WQT + d*128 + j] = Wq[idx]; return; }
  idx -= 16384;
  if (idx < 16384) { int j = idx >> 7, d = idx & 127; ws[OFF_WKT + d*128 + j] = Wk[idx]; return; }
  idx -= 16384;
  if (idx < 49152) { int j = idx >> 7, d = idx & 127; ws[OFF_WIHT + d*384 + j] = Wih[idx]; return; }
  idx -= 49152;
  if (idx < 49152) { int j = idx >> 7, d = idx & 127; ws[OFF_WHHT + d*384 + j] = Whh[idx]; return; }
  idx -= 49152;
  if (idx < 16384) { int j = idx >> 7, d = idx & 127; ws[OFF_WM1T + d*128 + j] = Wm1[idx]; return; }
  idx -= 16384;
  if (idx < 16384) { int j = idx >> 7, d = idx & 127; ws[OFF_WM2T + d*128 + j] = Wm2[idx]; return; }
  idx -= 16384;
  if (idx < 65536) { int j = idx >> 8, d = idx & 255; ws[OFF_WO1T + d*256 + j] = Wo1[idx]; return; }
  idx -= 65536;
  if (idx < 32768) { int j = idx >> 8, m = idx & 255; ws[OFF_WO2T + m*128 + j] = Wo2[idx]; return; }
  idx -= 32768;
  if (idx < 32768) { int c = idx & 255; ws[OFF_SLOTS + idx] = smu[c] + expf(sls[c]) * noise[idx]; return; }
  idx -= 32768;
  if (idx < 128) { ws[OFF_PI + idx] = 0.125f; }
}

// ---------------------------------------------------------------------------
// k = LN(inputs) @ Wk.T : 32 rows/block, 1024 blocks, 256 thr.
// x transposed into LDS (XOR-swizzled columns); GEMM reads 4 uniform b128
// broadcasts per d (16 rows/thread), W coalesced b32 from global (L2-hot).
__global__ __launch_bounds__(256) void k_kernel(
    const float* __restrict__ xin, const float* __restrict__ g, const float* __restrict__ bb,
    const float* __restrict__ WkT, float* __restrict__ kout) {
  __shared__ float xsT[128][32];
  __shared__ float2 red[32][8];
  __shared__ float mrow[32], srow[32];
  int t = threadIdx.x;
  long long base = (long long)blockIdx.x * 32 * 128;
  int row = t >> 3, cg = t & 7;            // row 0..31, 16-float col group 0..7
  const float4* src = (const float4*)(xin + base + row * 128 + cg * 16);
  float4 v0 = src[0], v1 = src[1], v2 = src[2], v3 = src[3];
  const float4* g4p = (const float4*)(g + cg * 16);
  const float4* b4p = (const float4*)(bb + cg * 16);
  float4 g0 = g4p[0], g1 = g4p[1], g2 = g4p[2], g3 = g4p[3];
  float4 bv0 = b4p[0], bv1 = b4p[1], bv2 = b4p[2], bv3 = b4p[3];
  float vals[16];
  *(float4*)&vals[0]  = v0; *(float4*)&vals[4]  = v1;
  *(float4*)&vals[8]  = v2; *(float4*)&vals[12] = v3;
  float gl[16], bl[16];
  *(float4*)&gl[0] = g0; *(float4*)&gl[4] = g1; *(float4*)&gl[8] = g2; *(float4*)&gl[12] = g3;
  *(float4*)&bl[0] = bv0; *(float4*)&bl[4] = bv1; *(float4*)&bl[8] = bv2; *(float4*)&bl[12] = bv3;
  {
    float s = 0.f, ss = 0.f;
    #pragma unroll
    for (int i = 0; i < 16; ++i) { float v = vals[i]; s += v; ss = fmaf(v, v, ss); }
    red[row][cg] = make_float2(s, ss);
  }
  __syncthreads();
  if (t < 32) {
    float s = 0.f, ss = 0.f;
    #pragma unroll
    for (int c = 0; c < 8; ++c) { float2 p = red[t][c]; s += p.x; ss += p.y; }
    float m = s * (1.0f / 128.0f);
    float var = ss * (1.0f / 128.0f) - m * m;
    mrow[t] = m; srow[t] = rsqrtf(var + 1e-5f);
  }
  __syncthreads();
  {
    float m = mrow[row], is = srow[row];
    #pragma unroll
    for (int i = 0; i < 16; ++i) {
      int d = cg * 16 + i;
      int rs = row ^ (((d >> 2) & 7) << 2);
      xsT[d][rs] = (vals[i] - m) * is * gl[i] + bl[i];
    }
  }
  __syncthreads();
  // GEMM: j = t&127, rh = t>>7 -> rows rh*16..+15
  int j = t & 127, rh = t >> 7;
  int r0 = rh * 16;
  float acc[16];
  #pragma unroll
  for (int i = 0; i < 16; ++i) acc[i] = 0.f;
  #pragma unroll 4
  for (int d = 0; d < 128; ++d) {
    float wv = WkT[d * 128 + j];
    int X = ((d >> 2) & 7) << 2;
    #pragma unroll
    for (int gi = 0; gi < 4; ++gi) {
      int off = (r0 + gi * 4) ^ X;
      float4 xv = *(const float4*)&xsT[d][off];
      acc[gi * 4 + 0] = fmaf(xv.x, wv, acc[gi * 4 + 0]);
      acc[gi * 4 + 1] = fmaf(xv.y, wv, acc[gi * 4 + 1]);
      acc[gi * 4 + 2] = fmaf(xv.z, wv, acc[gi * 4 + 2]);
      acc[gi * 4 + 3] = fmaf(xv.w, wv, acc[gi * 4 + 3]);
    }
  }
  #pragma unroll
  for (int i = 0; i < 16; ++i) kout[base + (long long)(r0 + i) * 128 + j] = acc[i];
}

// ---------------------------------------------------------------------------
// S1 standalone (first iteration): LN(slots) -> mus, wA=iv, wB=-2*q*iv, cz=sum q^2*iv
__global__ __launch_bounds__(256) void s1_kernel(
    const float* __restrict__ slots, const float* __restrict__ g, const float* __restrict__ bb,
    const float* __restrict__ WqT, float* __restrict__ mus,
    float* __restrict__ wA, float* __restrict__ wB, float* __restrict__ cz) {
  __shared__ float sl[256];
  __shared__ float2 wr[4];
  __shared__ float qs_l[128], ivs_l[128];
  __shared__ float wrC[4];
  int t = threadIdx.x, bi = blockIdx.x;
  float v = slots[bi * 256 + t];
  float s = v, ss = v * v;
  #pragma unroll
  for (int o = 32; o > 0; o >>= 1) { s += __shfl_down(s, o); ss += __shfl_down(ss, o); }
  if ((t & 63) == 0) wr[t >> 6] = make_float2(s, ss);
  __syncthreads();
  float fs  = wr[0].x + wr[1].x + wr[2].x + wr[3].x;
  float fss = wr[0].y + wr[1].y + wr[2].y + wr[3].y;
  float m   = fs * (1.0f/256.0f);
  float var = fss * (1.0f/256.0f) - m * m;
  float isr = rsqrtf(var + 1e-5f);
  float sn  = (v - m) * isr * g[t] + bb[t];
  sl[t] = sn;
  __syncthreads();
  if (t < 128) {
    float acc = 0.f;
    #pragma unroll 4
    for (int d = 0; d < 128; ++d) acc = fmaf(sl[d], WqT[d * 128 + t], acc);
    qs_l[t] = acc;
    mus[bi * 128 + t] = sn;
  } else {
    int jj = t - 128;
    float acc = 0.f;
    #pragma unroll 4
    for (int d = 0; d < 128; ++d) acc = fmaf(sl[128 + d], WqT[d * 128 + jj], acc);
    ivs_l[jj] = expf(-2.0f * acc);
  }
  __syncthreads();
  float cp = 0.f;
  if (t < 128) {
    float iv = ivs_l[t], q = qs_l[t];
    wA[bi * 128 + t] = iv;
    wB[bi * 128 + t] = -2.0f * q * iv;
    cp = q * q * iv;
  }
  #pragma unroll
  for (int o = 32; o > 0; o >>= 1) cp += __shfl_down(cp, o);
  if ((t & 63) == 0) wrC[t >> 6] = cp;
  __syncthreads();
  if (t == 0) cz[bi] = wrC[0] + wrC[1];
}

// ---------------------------------------------------------------------------
// S2 v2: 64-n chunk per block, 512 thr, NO k in LDS.
// phase1: dots[n,s] = sum_d k^2*wA + k*wB  (+cz later); k from global, w uniform.
// phase2: un/s2 partials; k re-read from global coalesced; gammas via LDS b128.
__global__ __launch_bounds__(512) void s2_kernel(
    const float* __restrict__ kmat, const float* __restrict__ wA,
    const float* __restrict__ wB,  const float* __restrict__ cz,
    const float* __restrict__ pi,
    float* __restrict__ wun, float* __restrict__ ws2, float* __restrict__ wden) {
  __shared__ float pdots[8][64][8];   // 16KB
  __shared__ float es[64][8];         // 2KB
  __shared__ float recip[64];
  __shared__ float gT[8][72];         // 2.3KB
  __shared__ float pd[8][8];
  __shared__ float pisl[8], czl[8];
  int t = threadIdx.x;
  int chunk = blockIdx.x, b = blockIdx.y;
  if (t < 8) { pisl[t] = pi[b * 8 + t]; czl[t] = cz[b * 8 + t]; }
  // ---- phase 1: thread (n = t&63, w = t>>6 -> d-chunk w*16)
  {
    int n = t & 63, w = t >> 6;
    const float4* kr4 = (const float4*)(kmat + (long long)((b * 2048 + chunk * 64 + n) * 128 + w * 16));
    const float4* wa4 = (const float4*)(wA + b * 1024);
    const float4* wb4 = (const float4*)(wB + b * 1024);
    float acc[8] = {0,0,0,0,0,0,0,0};
    #pragma unroll
    for (int dq = 0; dq < 4; ++dq) {
      float4 kv = kr4[dq];
      float xx = kv.x * kv.x, yy = kv.y * kv.y, zz = kv.z * kv.z, ww = kv.w * kv.w;
      #pragma unroll
      for (int s = 0; s < 8; ++s) {
        float4 a4 = wa4[s * 32 + w * 4 + dq];
        float4 b4 = wb4[s * 32 + w * 4 + dq];
        float ac = acc[s];
        ac = fmaf(xx, a4.x, ac); ac = fmaf(kv.x, b4.x, ac);
        ac = fmaf(yy, a4.y, ac); ac = fmaf(kv.y, b4.y, ac);
        ac = fmaf(zz, a4.z, ac); ac = fmaf(kv.z, b4.z, ac);
        ac = fmaf(ww, a4.w, ac); ac = fmaf(kv.w, b4.w, ac);
        acc[s] = ac;
      }
    }
    *(float4*)&pdots[w][n][0] = make_float4(acc[0], acc[1], acc[2], acc[3]);
    *(float4*)&pdots[w][n][4] = make_float4(acc[4], acc[5], acc[6], acc[7]);
  }
  __syncthreads();
  // ---- reduce over d-chunks + exp ; thread (n2 = t>>3, s = t&7)
  float e;
  {
    int n2 = t >> 3, s = t & 7;
    float dots = czl[s];
    #pragma unroll
    for (int w = 0; w < 8; ++w) dots += pdots[w][n2][s];
    e = (expf(-dots) + EPS_) * pisl[s];
    es[n2][s] = e;
  }
  __syncthreads();
  if (t < 64) {
    float ssum = 0.f;
    #pragma unroll
    for (int s = 0; s < 8; ++s) ssum += es[t][s];
    recip[t] = 1.0f / ssum;
  }
  __syncthreads();
  // ---- gammas + den partials
  {
    int n2 = t >> 3, s = t & 7;
    float gam = e * recip[n2];
    gT[s][n2] = gam;
    float p = gam;
    p += __shfl_down(p, 8); p += __shfl_down(p, 16); p += __shfl_down(p, 32);
    if ((t & 63) < 8) pd[t >> 6][t & 7] = p;
  }
  __syncthreads();
  if (t < 8) {
    float sden = 0.f;
    #pragma unroll
    for (int w = 0; w < 8; ++w) sden += pd[w][t];
    wden[(b * 32 + chunk) * 8 + t] = sden;
  }
  // ---- phase 2: thread (d = t&127, sh = t>>7 -> slots 2sh, 2sh+1)
  {
    int d = t & 127, sh = t >> 7;
    int s0 = sh * 2, s1 = s0 + 1;
    const float* kcol = kmat + (long long)(b * 2048 + chunk * 64) * 128 + d;
    float u0 = 0.f, u1 = 0.f, q0 = 0.f, q1 = 0.f;
    #pragma unroll 2
    for (int n3 = 0; n3 < 64; n3 += 4) {
      float4 ga = *(const float4*)&gT[s0][n3];
      float4 gb = *(const float4*)&gT[s1][n3];
      float k0 = kcol[(n3 + 0) * 128];
      float k1 = kcol[(n3 + 1) * 128];
      float k2 = kcol[(n3 + 2) * 128];
      float k3 = kcol[(n3 + 3) * 128];
      float k0s = k0 * k0, k1s = k1 * k1, k2s = k2 * k2, k3s = k3 * k3;
      u0 = fmaf(ga.x, k0, u0); q0 = fmaf(ga.x, k0s, q0);
      u1 = fmaf(gb.x, k0, u1); q1 = fmaf(gb.x, k0s, q1);
      u0 = fmaf(ga.y, k1, u0); q0 = fmaf(ga.y, k1s, q0);
      u1 = fmaf(gb.y, k1, u1); q1 = fmaf(gb.y, k1s, q1);
      u0 = fmaf(ga.z, k2, u0); q0 = fmaf(ga.z, k2s, q0);
      u1 = fmaf(gb.z, k2, u1); q1 = fmaf(gb.z, k2s, q1);
      u0 = fmaf(ga.w, k3, u0); q0 = fmaf(ga.w, k3s, q0);
      u1 = fmaf(gb.w, k3, u1); q1 = fmaf(gb.w, k3s, q1);
    }
    int pb = ((b * 32 + chunk) * 8) * 128 + d;
    wun[pb + s0 * 128] = u0; wun[pb + s1 * 128] = u1;
    ws2[pb + s0 * 128] = q0; ws2[pb + s1 * 128] = q1;
  }
}

// ---------------------------------------------------------------------------
// S3 fused: reduce(32 chunks) + GRU + LN + MLP + upd_ls + slots/pi; then
// next-iter S1 (emitting wA/wB/cz) or the final output MLP.
__global__ __launch_bounds__(512) void s3_kernel(
    const float* __restrict__ wun, const float* __restrict__ ws2, const float* __restrict__ wden,
    const float* __restrict__ WihT, const float* __restrict__ WhhT,
    const float* __restrict__ bih,  const float* __restrict__ bhh,
    const float* __restrict__ Wm1T, const float* __restrict__ bm1,
    const float* __restrict__ Wm2T, const float* __restrict__ bm2,
    const float* __restrict__ gmu,  const float* __restrict__ bmu,
    float* __restrict__ slots, float* __restrict__ pi,
    int do_s1,
    const float* __restrict__ gs, const float* __restrict__ bs,
    const float* __restrict__ WqT,
    float* __restrict__ mus, float* __restrict__ wAo, float* __restrict__ wBo,
    float* __restrict__ czo,
    const float* __restrict__ Wo1T, const float* __restrict__ bo1,
    const float* __restrict__ Wo2T, const float* __restrict__ bo2,
    float* __restrict__ out) {
  int t = threadIdx.x, bi = blockIdx.x;
  int d = t & 127, q = t >> 7;      // q in [0,4)
  int b = bi >> 3, i = bi & 7;
  __shared__ float redU[4][128], redS[4][128];
  __shared__ float dred[32];
  __shared__ float xs[128], hs[128];
  __shared__ float gacc[4][6][128];
  __shared__ float ga[6][128];
  __shared__ float grus[128], hl[128], m1s[128];
  __shared__ float macc[4][128];
  __shared__ float2 wr2[2];
  __shared__ float uarr[256];
  float unp = 0.f, s2p = 0.f;
  #pragma unroll
  for (int c = q * 8; c < q * 8 + 8; ++c) {
    int po = ((b * 32 + c) * 8 + i) * 128 + d;
    unp += wun[po]; s2p += ws2[po];
  }
  redU[q][d] = unp; redS[q][d] = s2p;
  if (t < 32) dred[t] = wden[(b * 32 + t) * 8 + i];
  if (q == 1) hs[d] = mus[bi * 128 + d];
  __syncthreads();
  float den = 0.f;
  #pragma unroll
  for (int c = 0; c < 32; ++c) den += dred[c];
  float un  = redU[0][d] + redU[1][d] + redU[2][d] + redU[3][d];
  float s2v = redS[0][d] + redS[1][d] + redS[2][d] + redS[3][d];
  if (q == 0) xs[d] = un / den;
  __syncthreads();
  {
    float a0 = 0, a1 = 0, a2 = 0, a3 = 0, a4 = 0, a5 = 0;
    #pragma unroll 4
    for (int dd = q * 32; dd < q * 32 + 32; ++dd) {
      float xv = xs[dd], hv = hs[dd];
      const float* wi = &WihT[dd * 384 + d];
      const float* wh = &WhhT[dd * 384 + d];
      a0 = fmaf(xv, wi[0],   a0);
      a1 = fmaf(xv, wi[128], a1);
      a2 = fmaf(xv, wi[256], a2);
      a3 = fmaf(hv, wh[0],   a3);
      a4 = fmaf(hv, wh[128], a4);
      a5 = fmaf(hv, wh[256], a5);
    }
    gacc[q][0][d] = a0; gacc[q][1][d] = a1; gacc[q][2][d] = a2;
    gacc[q][3][d] = a3; gacc[q][4][d] = a4; gacc[q][5][d] = a5;
  }
  __syncthreads();
  for (int f = t; f < 768; f += 512) {
    int j = f >> 7, dd = f & 127;
    ga[j][dd] = gacc[0][j][dd] + gacc[1][j][dd] + gacc[2][j][dd] + gacc[3][j][dd];
  }
  __syncthreads();
  float gru = 0.f;
  if (q == 0) {
    float ir = ga[0][d] + bih[d], iz = ga[1][d] + bih[128 + d], inn = ga[2][d] + bih[256 + d];
    float hr = ga[3][d] + bhh[d], hz = ga[4][d] + bhh[128 + d], hn  = ga[5][d] + bhh[256 + d];
    float r  = 1.0f / (1.0f + expf(-(ir + hr)));
    float z  = 1.0f / (1.0f + expf(-(iz + hz)));
    float nn = tanhf(inn + r * hn);
    gru = (1.0f - z) * nn + z * hs[d];
    grus[d] = gru;
    float s = gru, ssq = gru * gru;
    #pragma unroll
    for (int o = 32; o > 0; o >>= 1) { s += __shfl_down(s, o); ssq += __shfl_down(ssq, o); }
    if ((d & 63) == 0) wr2[d >> 6] = make_float2(s, ssq);
  }
  __syncthreads();
  if (q == 0) {
    float fs = wr2[0].x + wr2[1].x, fss = wr2[0].y + wr2[1].y;
    float mean = fs * (1.0f/128.0f);
    float var  = fss * (1.0f/128.0f) - mean * mean;
    hl[d] = (gru - mean) * rsqrtf(var + 1e-5f) * gmu[d] + bmu[d];
  }
  __syncthreads();
  {
    float m1p = 0.f;
    #pragma unroll 4
    for (int dd = q * 32; dd < q * 32 + 32; ++dd)
      m1p = fmaf(hl[dd], Wm1T[dd * 128 + d], m1p);
    macc[q][d] = m1p;
  }
  __syncthreads();
  if (q == 0) m1s[d] = fmaxf(macc[0][d] + macc[1][d] + macc[2][d] + macc[3][d] + bm1[d], 0.f);
  __syncthreads();
  {
    float m2p = 0.f;
    #pragma unroll 4
    for (int dd = q * 32; dd < q * 32 + 32; ++dd)
      m2p = fmaf(m1s[dd], Wm2T[dd * 128 + d], m2p);
    macc[q][d] = m2p;
  }
  __syncthreads();
  if (q == 0) {
    float u = grus[d] + macc[0][d] + macc[1][d] + macc[2][d] + macc[3][d] + bm2[d];
    float val = (s2v - 2.0f * u * un + u * u * den) / den;
    float ls = 0.5f * logf(fmaxf(val, 0.0f) + EPS_);
    slots[bi * 256 + d]       = u;
    slots[bi * 256 + 128 + d] = ls;
    uarr[d] = u; uarr[128 + d] = ls;
    if (d == 0) pi[bi] = den;
  }
  __syncthreads();
  if (do_s1) {
    __shared__ float2 wr4[4];
    __shared__ float sln[256];
    __shared__ float qacc[2][2][128];
    __shared__ float qs_l[128], ivs_l[128];
    __shared__ float wrC[8];
    if (t < 256) {
      float v = uarr[t];
      float s = v, ssq = v * v;
      #pragma unroll
      for (int o = 32; o > 0; o >>= 1) { s += __shfl_down(s, o); ssq += __shfl_down(ssq, o); }
      if ((t & 63) == 0) wr4[t >> 6] = make_float2(s, ssq);
    }
    __syncthreads();
    if (t < 256) {
      float fs  = wr4[0].x + wr4[1].x + wr4[2].x + wr4[3].x;
      float fss = wr4[0].y + wr4[1].y + wr4[2].y + wr4[3].y;
      float m   = fs * (1.0f/256.0f);
      float var = fss * (1.0f/256.0f) - m * m;
      sln[t] = (uarr[t] - m) * rsqrtf(var + 1e-5f) * gs[t] + bs[t];
    }
    __syncthreads();
    {
      int h2 = t >> 8, qq = (t >> 7) & 1, d2 = t & 127;
      const float* src = sln + h2 * 128;
      float acc = 0.f;
      #pragma unroll 4
      for (int dd = qq * 64; dd < qq * 64 + 64; ++dd)
        acc = fmaf(src[dd], WqT[dd * 128 + d2], acc);
      qacc[h2][qq][d2] = acc;
    }
    __syncthreads();
    if (t < 128) {
      qs_l[t] = qacc[0][0][t] + qacc[0][1][t];
      mus[bi * 128 + t] = sln[t];
    } else if (t < 256) {
      int dd2 = t - 128;
      ivs_l[dd2] = expf(-2.0f * (qacc[1][0][dd2] + qacc[1][1][dd2]));
    }
    __syncthreads();
    float cp = 0.f;
    if (t < 128) {
      float iv = ivs_l[t], qv = qs_l[t];
      wAo[bi * 128 + t] = iv;
      wBo[bi * 128 + t] = -2.0f * qv * iv;
      cp = qv * qv * iv;
    }
    #pragma unroll
    for (int o = 32; o > 0; o >>= 1) cp += __shfl_down(cp, o);
    if ((t & 63) == 0) wrC[t >> 6] = cp;
    __syncthreads();
    if (t == 0) czo[bi] = wrC[0] + wrC[1];
  } else {
    __shared__ float oacc[2][256];
    __shared__ float hh[256];
    {
      int o = t & 255, qq = t >> 8;
      float acc = 0.f;
      #pragma unroll 4
      for (int dd = qq * 128; dd < qq * 128 + 128; ++dd)
        acc = fmaf(uarr[dd], Wo1T[dd * 256 + o], acc);
      oacc[qq][o] = acc;
    }
    __syncthreads();
    if (t < 256) hh[t] = fmaxf(oacc[0][t] + oacc[1][t] + bo1[t], 0.f);
    __syncthreads();
    {
      int o2 = t & 127, q4 = t >> 7;
      float acc2 = 0.f;
      #pragma unroll 4
      for (int dd = q4 * 64; dd < q4 * 64 + 64; ++dd)
        acc2 = fmaf(hh[dd], Wo2T[dd * 128 + o2], acc2);
      macc[q4][o2] = acc2;
    }
    __syncthreads();
    if (t < 128) out[bi * 128 + t] = macc[0][t] + macc[1][t] + macc[2][t] + macc[3][t] + bo2[t];
  }
}

// ---------------------------------------------------------------------------
extern "C" void kernel_launch(void* const* d_in, const int* in_sizes, int n_in,
                              void* d_out, int out_size, void* d_ws, size_t ws_size,
                              hipStream_t stream) {
  const float* inputs = (const float*)d_in[0];
  const float* noise  = (const float*)d_in[1];
  const float* smu    = (const float*)d_in[2];
  const float* sls    = (const float*)d_in[3];
  const float* Wq     = (const float*)d_in[4];
  const float* Wk     = (const float*)d_in[5];
  const float* Wih    = (const float*)d_in[6];
  const float* Whh    = (const float*)d_in[7];
  const float* bih    = (const float*)d_in[8];
  const float* bhh    = (const float*)d_in[9];
  const float* Wm1    = (const float*)d_in[10];
  const float* bm1    = (const float*)d_in[11];
  const float* Wm2    = (const float*)d_in[12];
  const float* bm2    = (const float*)d_in[13];
  const float* gin    = (const float*)d_in[14];
  const float* bin    = (const float*)d_in[15];
  const float* gsl    = (const float*)d_in[16];
  const float* bsl    = (const float*)d_in[17];
  const float* gmu    = (const float*)d_in[18];
  const float* bmu    = (const float*)d_in[19];
  const float* Wo1    = (const float*)d_in[20];
  const float* bo1    = (const float*)d_in[21];
  const float* Wo2    = (const float*)d_in[22];
  const float* bo2    = (const float*)d_in[23];

  float* ws    = (float*)d_ws;
  float* kbuf  = ws + OFF_K;
  float* WqT   = ws + OFF_WQT;
  float* WkT   = ws + OFF_WKT;
  float* WihT  = ws + OFF_WIHT;
  float* WhhT  = ws + OFF_WHHT;
  float* Wm1T  = ws + OFF_WM1T;
  float* Wm2T  = ws + OFF_WM2T;
  float* Wo1T  = ws + OFF_WO1T;
  float* Wo2T  = ws + OFF_WO2T;
  float* slots = ws + OFF_SLOTS;
  float* pibuf = ws + OFF_PI;
  float* mus   = ws + OFF_MUS;
  float* wA    = ws + OFF_WA;
  float* wB    = ws + OFF_WB;
  float* wun   = ws + OFF_UN;
  float* ws2   = ws + OFF_S2;
  float* wden  = ws + OFF_DEN;
  float* czb   = ws + OFF_CZ;

  hipLaunchKernelGGL(init_kernel, dim3(1153), dim3(256), 0, stream,
                     Wq, Wk, Wih, Whh, Wm1, Wm2, Wo1, Wo2, smu, sls, noise, ws);
  hipLaunchKernelGGL(k_kernel, dim3(1024), dim3(256), 0, stream,
                     inputs, gin, bin, WkT, kbuf);
  hipLaunchKernelGGL(s1_kernel, dim3(128), dim3(256), 0, stream,
                     slots, gsl, bsl, WqT, mus, wA, wB, czb);
  for (int s = 0; s < 4; ++s) {
    hipLaunchKernelGGL(s2_kernel, dim3(32, 16), dim3(512), 0, stream,
                       kbuf, wA, wB, czb, pibuf, wun, ws2, wden);
    hipLaunchKernelGGL(s3_kernel, dim3(128), dim3(512), 0, stream,
                       wun, ws2, wden, WihT, WhhT, bih, bhh,
                       Wm1T, bm1, Wm2T, bm2, gmu, bmu, slots, pibuf,
                       (s < 3) ? 1 : 0, gsl, bsl, WqT, mus, wA, wB, czb,
                       Wo1T, bo1, Wo2T, bo2, (float*)d_out);
  }
}